// Round 4
// baseline (62.306 us; speedup 1.0000x reference)
//
#include <hip/hip_runtime.h>
#include <hip/hip_bf16.h>
#include <math.h>

// GAT layer: B=8, N=2048, D_IN=128, D_OUT=64, fp32.
// Round 4: WAVE-per-row, no barriers on the adj critical path. Each wave
// issues all 8 adj float4 loads up-front (-> deep HBM pipeline across
// ~24 waves/CU), compacts nonzeros via ballot+mbcnt into its private LDS
// list, does a pure wave-level softmax (no block reduce), then gathers.

#define GAT_B 8
#define GAT_N 2048
#define GAT_DIN 128
#define GAT_DOUT 64
#define GAT_CAP 192   // per-row neighbor list capacity (row nnz ~42 +- 6.4)

// ---------------- Kernel 1: wh = h @ w, s1, s2 ----------------
__global__ __launch_bounds__(256) void gat_wh_kernel(
    const float* __restrict__ h, const float* __restrict__ w,
    const float* __restrict__ a, float* __restrict__ wh,
    float* __restrict__ s1, float* __restrict__ s2) {
  __shared__ float w_lds[GAT_DIN * GAT_DOUT];   // 32 KB
  __shared__ float h_lds[4][GAT_DIN];           // 2 KB

  for (int t = threadIdx.x; t < (GAT_DIN * GAT_DOUT) / 4; t += 256)
    ((float4*)w_lds)[t] = ((const float4*)w)[t];

  const int lane = threadIdx.x & 63;
  const int wv = threadIdx.x >> 6;
  const float a1 = a[lane];
  const float a2 = a[GAT_DOUT + lane];

  const int ngroups = (GAT_B * GAT_N) / 4;  // 4096 groups of 4 rows
  for (int rg = blockIdx.x; rg < ngroups; rg += gridDim.x) {
    __syncthreads();
    const float4* hsrc = (const float4*)(h + (size_t)rg * 4 * GAT_DIN);
    for (int t = threadIdx.x; t < (4 * GAT_DIN) / 4; t += 256)
      ((float4*)&h_lds[0][0])[t] = hsrc[t];
    __syncthreads();

    const int row = rg * 4 + wv;
    float acc = 0.f;
#pragma unroll 16
    for (int d = 0; d < GAT_DIN; ++d)
      acc = fmaf(h_lds[wv][d], w_lds[d * GAT_DOUT + lane], acc);

    wh[(size_t)row * GAT_DOUT + lane] = acc;

    float t1 = acc * a1, t2 = acc * a2;
#pragma unroll
    for (int off = 32; off >= 1; off >>= 1) {
      t1 += __shfl_xor(t1, off);
      t2 += __shfl_xor(t2, off);
    }
    if (lane == 0) { s1[row] = t1; s2[row] = t2; }
  }
}

// ---------------- Kernel 2: wave-per-row sparse aggregation -----------------
// grid = 4096 blocks: blockIdx = b*512 + g; block handles rows b*2048+g*4+wv.
// All 4 rows of a block share batch b -> s2 staged once per block.
__global__ __launch_bounds__(256) void gat_row_kernel(
    const float* __restrict__ adj, const float* __restrict__ wh,
    const float* __restrict__ s1, const float* __restrict__ s2,
    float* __restrict__ out) {
  __shared__ float s2_lds[GAT_N];                 // 8 KB
  __shared__ float sc_l[4][GAT_CAP];              // 3 KB
  __shared__ unsigned short idx_l[4][GAT_CAP];    // 1.5 KB

  const int lane = threadIdx.x & 63;
  const int wv = threadIdx.x >> 6;
  const int b = blockIdx.x >> 9;                  // batch
  const int g = blockIdx.x & 511;
  const int row = (b << 11) + g * 4 + wv;

  const float* adj_row = adj + (size_t)row * GAT_N;
  const float* whb = wh + ((size_t)b << 11) * GAT_DOUT;

  // Issue ALL 8 adj float4 loads up-front: 8 independent 1KB wave-loads
  // in flight before anything else; nothing below depends on them until
  // the ballot loop.
  float4 av[8];
#pragma unroll
  for (int u = 0; u < 8; ++u)
    av[u] = *(const float4*)(adj_row + u * 256 + lane * 4);

  // Stage this batch's s2 row (8 KB) once per block.
  {
    const float4* src = (const float4*)(s2 + ((size_t)b << 11));
    float4* dst = (float4*)s2_lds;
    dst[threadIdx.x] = src[threadIdx.x];
    dst[threadIdx.x + 256] = src[threadIdx.x + 256];
  }
  const float s1i = s1[row];
  __syncthreads();

  // Ballot+mbcnt compaction of nonzero (j, score) into this wave's list.
  int base = 0;
  float cmax = -1e30f;
  float* my_sc = sc_l[wv];
  unsigned short* my_idx = idx_l[wv];
#pragma unroll
  for (int u = 0; u < 8; ++u) {
#pragma unroll
    for (int comp = 0; comp < 4; ++comp) {
      const float a_c = (comp == 0) ? av[u].x : (comp == 1) ? av[u].y
                       : (comp == 2) ? av[u].z : av[u].w;
      const bool pred = a_c > 0.f;
      const unsigned long long msk = __ballot(pred);
      if (msk) {  // wave-uniform
        const int prefix = __builtin_amdgcn_mbcnt_hi(
            (unsigned)(msk >> 32),
            __builtin_amdgcn_mbcnt_lo((unsigned)msk, 0u));
        if (pred) {
          const int p = base + prefix;
          if (p < GAT_CAP) {   // clamp: no OOB even in absurd-density rows
            const int j = u * 256 + lane * 4 + comp;
            float sc = s1i + s2_lds[j];
            sc = (sc >= 0.f) ? sc : 0.2f * sc;   // LeakyReLU(0.2)
            my_sc[p] = sc;
            my_idx[p] = (unsigned short)j;
            cmax = fmaxf(cmax, sc);
          }
        }
        base += (int)__popcll(msk);
      }
    }
  }
  base = min(base, GAT_CAP);

  // Wave max == row max (wave owns the whole row; self-loop => base >= 1).
#pragma unroll
  for (int off = 32; off >= 1; off >>= 1)
    cmax = fmaxf(cmax, __shfl_xor(cmax, off));
  const float m = cmax;

  // exp + gather, dual accumulators for ILP; gathers are independent 256B
  // coalesced L2/L3 reads.
  float l0 = 0.f, l1 = 0.f, acc0 = 0.f, acc1 = 0.f;
  int t = 0;
  for (; t + 2 <= base; t += 2) {
    const float e0 = __expf(my_sc[t] - m);
    const float e1 = __expf(my_sc[t + 1] - m);
    const int j0 = my_idx[t];
    const int j1 = my_idx[t + 1];
    l0 += e0;
    l1 += e1;
    acc0 = fmaf(e0, whb[(size_t)j0 * GAT_DOUT + lane], acc0);
    acc1 = fmaf(e1, whb[(size_t)j1 * GAT_DOUT + lane], acc1);
  }
  if (t < base) {
    const float e0 = __expf(my_sc[t] - m);
    const int j0 = my_idx[t];
    l0 += e0;
    acc0 = fmaf(e0, whb[(size_t)j0 * GAT_DOUT + lane], acc0);
  }

  out[(size_t)row * GAT_DOUT + lane] = (acc0 + acc1) / (l0 + l1);
}

extern "C" void kernel_launch(void* const* d_in, const int* in_sizes, int n_in,
                              void* d_out, int out_size, void* d_ws, size_t ws_size,
                              hipStream_t stream) {
  const float* h   = (const float*)d_in[0];  // (8, 2048, 128)
  const float* adj = (const float*)d_in[1];  // (8, 2048, 2048)
  const float* w   = (const float*)d_in[2];  // (128, 64)
  const float* a   = (const float*)d_in[3];  // (128, 1)
  float* out = (float*)d_out;                // (8, 2048, 64)

  const size_t rows = (size_t)GAT_B * GAT_N;           // 16384
  float* wh = (float*)d_ws;                            // rows*64 floats = 4 MB
  float* s1 = wh + rows * GAT_DOUT;                    // 64 KB
  float* s2 = s1 + rows;                               // 64 KB

  gat_wh_kernel<<<1024, 256, 0, stream>>>(h, w, a, wh, s1, s2);
  // 4096 blocks = 8 batches x 512; 4 waves/block, one ROW per wave.
  gat_row_kernel<<<GAT_B * (GAT_N / 4), 256, 0, stream>>>(adj, wh, s1, s2, out);
}